// Round 3
// baseline (1293.530 us; speedup 1.0000x reference)
//
#include <hip/hip_runtime.h>

// StructuredElmanCell — per-scalar-state recurrence chains.
// H[b,h,n,p] <- silu(alpha[t,b,h]*H + sum_r B[t,b,h,n,r]*X[t,b,h,p,r])
// y[t,b,h*HD+p] = sum_n H_new ; out = y*silu(z+y)  (gate applied in pass 2)
// One thread per (b,h,p,n). Wave = 2 p x 32 n -> n-reduction via DPP.
// Depth-4 register prefetch pipeline to cover ~900cy HBM latency
// (occupancy is grid-pinned at 4 waves/SIMD, so ILP is the only lever).

namespace {
constexpr int T  = 1024;
constexpr int BS = 4;
constexpr int NH = 16;
constexpr int DS = 32;
constexpr int HD = 128;
constexpr int R  = 8;
constexpr int DI = NH * HD;              // 2048

// strides per timestep, in float4 / float units
constexpr unsigned B4_T = BS * NH * DS * R / 4;   // 4096 float4
constexpr unsigned X4_T = BS * NH * HD * R / 4;   // 16384 float4
constexpr unsigned A_T  = BS * NH;                // 64 floats
constexpr unsigned Y_T  = BS * DI;                // 8192 floats

constexpr float LOG2E = 1.4426950408889634f;

__device__ __forceinline__ float fast_exp(float x) {
    return __builtin_amdgcn_exp2f(x * LOG2E);
}
__device__ __forceinline__ float fast_silu(float x) {
    float e = __builtin_amdgcn_exp2f(x * -LOG2E);
    return x * __builtin_amdgcn_rcpf(1.0f + e);
}

template<int CTRL>
__device__ __forceinline__ float dpp_add(float v) {
    int s = __builtin_amdgcn_update_dpp(0, __float_as_int(v), CTRL, 0xF, 0xF, true);
    return v + __int_as_float(s);
}
// Sum over each 32-lane half; totals land in lanes 31 and 63.
__device__ __forceinline__ float group32_sum_to_lane31(float y) {
    y = dpp_add<0x111>(y);   // row_shr:1
    y = dpp_add<0x112>(y);   // row_shr:2
    y = dpp_add<0x114>(y);   // row_shr:4
    y = dpp_add<0x118>(y);   // row_shr:8
    y = dpp_add<0x142>(y);   // row_bcast15 -> lanes 31/63 hold 32-sums
    return y;
}

// ---------------- pass 0: alpha = 1/(2+exp(ar+ab)) -------------------------
__global__ __launch_bounds__(256)
void alpha_kernel(const float* __restrict__ ar_, const float* __restrict__ ab_,
                  float* __restrict__ alpha_) {
    int i = blockIdx.x * 256 + threadIdx.x;          // [T,BS,NH] flat
    float v = ar_[i] + ab_[i & (NH - 1)];
    alpha_[i] = __builtin_amdgcn_rcpf(2.0f + fast_exp(v));  // == sigmoid(-softplus)
}

// ---------------- pass 1: the scan, emits raw y sums -----------------------
template<bool PRE>
__global__ __launch_bounds__(256, 4)
void elman_scan_kernel(const float4* __restrict__ B4,
                       const float4* __restrict__ X4,
                       const float*  __restrict__ a_,   // PRE? alpha : alpha_raw
                       const float*  __restrict__ ab_,
                       const float*  __restrict__ H0_,
                       float* __restrict__ y_,          // [T,BS,DI] raw sums
                       float* __restrict__ Hf_)
{
    const int tid  = blockIdx.x * 256 + threadIdx.x;
    const int lane = threadIdx.x & 63;
    const int n    = lane & 31;        // state row within DS
    const int pl   = lane >> 5;
    const int w    = tid >> 6;
    const int bh   = w >> 6;           // 64 waves per (b,h)
    const int wp   = w & 63;
    const int p    = wp * 2 + pl;      // 0..127
    const int h    = bh & (NH - 1);
    const int b    = bh >> 4;
    const bool owner = (n == 31);

    const float ab = PRE ? 0.0f : ab_[h];

    float H = H0_[((size_t)bh * DS + n) * HD + p];

    // 32-bit element offsets off SGPR bases (1 VALU per bump, not 2)
    const unsigned iB = (unsigned)bh * 64u  + (unsigned)n * 2u;   // float4 units
    const unsigned iX = (unsigned)bh * 256u + (unsigned)p * 2u;   // float4 units
    const unsigned iY = (unsigned)b * DI + (unsigned)h * HD + (unsigned)p;
    const unsigned iA = (unsigned)__builtin_amdgcn_readfirstlane(bh); // uniform

    // ---- 4-stage register pipeline ----
    float4 sb0[4], sb1[4], sx0[4], sx1[4];
    float  sal[4];
    #pragma unroll
    for (int s = 0; s < 4; ++s) {
        sb0[s] = B4[iB + (unsigned)s * B4_T];
        sb1[s] = B4[iB + (unsigned)s * B4_T + 1u];
        sx0[s] = X4[iX + (unsigned)s * X4_T];
        sx1[s] = X4[iX + (unsigned)s * X4_T + 1u];
        sal[s] = a_[iA + (unsigned)s * A_T];
    }

    auto step = [&](float4 b0, float4 b1, float4 x0, float4 x1,
                    float ca, unsigned yoff) {
        float u0 =      b0.x * x0.x;
        u0 = fmaf(b0.z, x0.z, u0);
        u0 = fmaf(b1.x, x1.x, u0);
        u0 = fmaf(b1.z, x1.z, u0);
        float u1 =      b0.y * x0.y;
        u1 = fmaf(b0.w, x0.w, u1);
        u1 = fmaf(b1.y, x1.y, u1);
        u1 = fmaf(b1.w, x1.w, u1);
        float alpha = PRE ? ca
                          : __builtin_amdgcn_rcpf(2.0f + fast_exp(ca + ab));
        float hpre = fmaf(alpha, H, u0 + u1);
        H = fast_silu(hpre);
        float y = group32_sum_to_lane31(H);
        if (owner) y_[yoff] = y;
    };

    // running prefetch bases (timestep t+4 when loop var is t)
    unsigned pB = iB + 4u * B4_T;
    unsigned pX = iX + 4u * X4_T;
    unsigned pA = iA + 4u * A_T;
    unsigned pY = iY;

    int t = 0;
    for (; t <= T - 8; t += 4) {
        #pragma unroll
        for (int s = 0; s < 4; ++s) {
            // snapshot stage s, then immediately refill with t+s+4
            float4 cb0 = sb0[s], cb1 = sb1[s], cx0 = sx0[s], cx1 = sx1[s];
            float  ca  = sal[s];
            sb0[s] = B4[pB + (unsigned)s * B4_T];
            sb1[s] = B4[pB + (unsigned)s * B4_T + 1u];
            sx0[s] = X4[pX + (unsigned)s * X4_T];
            sx1[s] = X4[pX + (unsigned)s * X4_T + 1u];
            sal[s] = a_[pA + (unsigned)s * A_T];
            step(cb0, cb1, cx0, cx1, ca, pY + (unsigned)s * Y_T);
        }
        pB += 4u * B4_T;
        pX += 4u * X4_T;
        pA += 4u * A_T;
        pY += 4u * Y_T;
    }
    // tail: stages hold t=T-4..T-1, no prefetch
    #pragma unroll
    for (int s = 0; s < 4; ++s) {
        step(sb0[s], sb1[s], sx0[s], sx1[s], sal[s], pY + (unsigned)s * Y_T);
    }

    Hf_[((size_t)bh * DS + n) * HD + p] = H;
}

// ---------------- pass 2: out = y * silu(z + y), in place ------------------
__global__ __launch_bounds__(256)
void gate_kernel(float* __restrict__ y_, const float* __restrict__ z_) {
    int i = blockIdx.x * 256 + threadIdx.x;          // float4 index
    float4 y4 = ((const float4*)y_)[i];
    float4 z4 = ((const float4*)z_)[i];
    float4 o;
    o.x = y4.x * fast_silu(z4.x + y4.x);
    o.y = y4.y * fast_silu(z4.y + y4.y);
    o.z = y4.z * fast_silu(z4.z + y4.z);
    o.w = y4.w * fast_silu(z4.w + y4.w);
    ((float4*)y_)[i] = o;
}
} // namespace

extern "C" void kernel_launch(void* const* d_in, const int* in_sizes, int n_in,
                              void* d_out, int out_size, void* d_ws, size_t ws_size,
                              hipStream_t stream) {
    const float* B_proj     = (const float*)d_in[0];
    const float* X_proj     = (const float*)d_in[1];
    const float* alpha_raw  = (const float*)d_in[2];
    const float* alpha_bias = (const float*)d_in[3];
    const float* z          = (const float*)d_in[4];
    const float* H0         = (const float*)d_in[5];

    float* out = (float*)d_out;                       // [T,BS,DI] then Hf
    float* Hf  = out + (size_t)T * BS * DI;

    const size_t alpha_bytes = (size_t)T * BS * NH * sizeof(float);
    if (ws_size >= alpha_bytes) {
        float* aw = (float*)d_ws;
        alpha_kernel<<<T * BS * NH / 256, 256, 0, stream>>>(alpha_raw, alpha_bias, aw);
        elman_scan_kernel<true><<<1024, 256, 0, stream>>>(
            (const float4*)B_proj, (const float4*)X_proj, aw, alpha_bias, H0, out, Hf);
    } else {
        elman_scan_kernel<false><<<1024, 256, 0, stream>>>(
            (const float4*)B_proj, (const float4*)X_proj, alpha_raw, alpha_bias, H0, out, Hf);
    }
    gate_kernel<<<(T * BS * DI / 4) / 256, 256, 0, stream>>>(out, z);
}

// Round 4
// 734.302 us; speedup vs baseline: 1.7616x; 1.7616x over previous
//
#include <hip/hip_runtime.h>

// StructuredElmanCell — per-scalar-state recurrence chains.
// H[b,h,n,p] <- silu(alpha[t,b,h]*H + sum_r B[t,b,h,n,r]*X[t,b,h,p,r])
// y[t,b,h*HD+p] = sum_n H_new ; out = y*silu(z+y)  (gate applied in pass 2)
// One thread per (b,h,p,n). Wave = 2 p x 32 n -> n-reduction via DPP.
// Depth-4 rotating register pipeline, consume-then-refill IN PLACE so peak
// liveness stays ~90 VGPR (R3's snapshot variant spilled to scratch).

namespace {
constexpr int T  = 1024;
constexpr int BS = 4;
constexpr int NH = 16;
constexpr int DS = 32;
constexpr int HD = 128;
constexpr int R  = 8;
constexpr int DI = NH * HD;              // 2048

// per-timestep strides, in float4 / float units
constexpr unsigned B4_T = BS * NH * DS * R / 4;   // 4096 float4
constexpr unsigned X4_T = BS * NH * HD * R / 4;   // 16384 float4
constexpr unsigned A_T  = BS * NH;                // 64 floats
constexpr unsigned Y_T  = BS * DI;                // 8192 floats

constexpr float LOG2E = 1.4426950408889634f;

__device__ __forceinline__ float fast_exp(float x) {
    return __builtin_amdgcn_exp2f(x * LOG2E);
}
__device__ __forceinline__ float fast_silu(float x) {
    float e = __builtin_amdgcn_exp2f(x * -LOG2E);
    return x * __builtin_amdgcn_rcpf(1.0f + e);
}

template<int CTRL>
__device__ __forceinline__ float dpp_add(float v) {
    int s = __builtin_amdgcn_update_dpp(0, __float_as_int(v), CTRL, 0xF, 0xF, true);
    return v + __int_as_float(s);
}
// Sum over each 32-lane half; totals land in lanes 31 and 63.
__device__ __forceinline__ float group32_sum_to_lane31(float y) {
    y = dpp_add<0x111>(y);   // row_shr:1
    y = dpp_add<0x112>(y);   // row_shr:2
    y = dpp_add<0x114>(y);   // row_shr:4
    y = dpp_add<0x118>(y);   // row_shr:8
    y = dpp_add<0x142>(y);   // row_bcast15 -> lanes 31/63 hold 32-sums
    return y;
}

struct Stage {
    float4 b0, b1, x0, x1;
    float  al;
};

// ---------------- pass 0: alpha = 1/(2+exp(ar+ab)) -------------------------
__global__ __launch_bounds__(256)
void alpha_kernel(const float* __restrict__ ar_, const float* __restrict__ ab_,
                  float* __restrict__ alpha_) {
    int i = blockIdx.x * 256 + threadIdx.x;          // [T,BS,NH] flat
    float v = ar_[i] + ab_[i & (NH - 1)];
    alpha_[i] = __builtin_amdgcn_rcpf(2.0f + fast_exp(v));  // == sigmoid(-softplus)
}

// ---------------- pass 1: the scan, emits raw y sums -----------------------
template<bool PRE>
__global__ __launch_bounds__(256, 4)
void elman_scan_kernel(const float4* __restrict__ B4,
                       const float4* __restrict__ X4,
                       const float*  __restrict__ a_,   // PRE? alpha : alpha_raw
                       const float*  __restrict__ ab_,
                       const float*  __restrict__ H0_,
                       float* __restrict__ y_,          // [T,BS,DI] raw sums
                       float* __restrict__ Hf_)
{
    const int tid  = blockIdx.x * 256 + threadIdx.x;
    const int lane = threadIdx.x & 63;
    const int n    = lane & 31;        // state row within DS
    const int pl   = lane >> 5;
    const int w    = tid >> 6;
    const int bh   = w >> 6;           // 64 waves per (b,h)
    const int wp   = w & 63;
    const int p    = wp * 2 + pl;      // 0..127
    const int h    = bh & (NH - 1);
    const int b    = bh >> 4;
    const bool owner = (n == 31);

    const float ab = PRE ? 0.0f : ab_[h];

    float H = H0_[((size_t)bh * DS + n) * HD + p];

    // base 32-bit element offsets (saddr-form loads off SGPR base)
    const unsigned iB = (unsigned)bh * 64u  + (unsigned)n * 2u;   // float4 units
    const unsigned iX = (unsigned)bh * 256u + (unsigned)p * 2u;   // float4 units
    const unsigned iY = (unsigned)b * DI + (unsigned)h * HD + (unsigned)p;
    const unsigned iA = (unsigned)__builtin_amdgcn_readfirstlane(bh); // uniform

    Stage stA, stB, stC, stD;

    auto refill = [&](Stage& s, unsigned oB, unsigned oX, unsigned oA) {
        s.b0 = B4[oB];
        s.b1 = B4[oB + 1u];
        s.x0 = X4[oX];
        s.x1 = X4[oX + 1u];
        s.al = a_[oA];
    };

    auto step = [&](const Stage& s, unsigned yoff) {
        float u0 =      s.b0.x * s.x0.x;
        u0 = fmaf(s.b0.z, s.x0.z, u0);
        u0 = fmaf(s.b1.x, s.x1.x, u0);
        u0 = fmaf(s.b1.z, s.x1.z, u0);
        float u1 =      s.b0.y * s.x0.y;
        u1 = fmaf(s.b0.w, s.x0.w, u1);
        u1 = fmaf(s.b1.y, s.x1.y, u1);
        u1 = fmaf(s.b1.w, s.x1.w, u1);
        float alpha = PRE ? s.al
                          : __builtin_amdgcn_rcpf(2.0f + fast_exp(s.al + ab));
        float hpre = fmaf(alpha, H, u0 + u1);
        H = fast_silu(hpre);
        float y = group32_sum_to_lane31(H);
        if (owner) y_[yoff] = y;
    };

    // prime: stages hold t = 0..3
    refill(stA, iB,            iX,            iA);
    refill(stB, iB + B4_T,     iX + X4_T,     iA + A_T);
    refill(stC, iB + 2 * B4_T, iX + 2 * X4_T, iA + 2 * A_T);
    refill(stD, iB + 3 * B4_T, iX + 3 * X4_T, iA + 3 * A_T);

    // running prefetch offsets: stage A's next timestep (t+4)
    unsigned oB = iB + 4u * B4_T;
    unsigned oX = iX + 4u * X4_T;
    unsigned oA = iA + 4u * A_T;
    unsigned oY = iY;

    #pragma unroll 1
    for (int t = 0; t <= T - 8; t += 4) {
        step(stA, oY);            refill(stA, oB,            oX,            oA);
        step(stB, oY + Y_T);      refill(stB, oB + B4_T,     oX + X4_T,     oA + A_T);
        step(stC, oY + 2 * Y_T);  refill(stC, oB + 2 * B4_T, oX + 2 * X4_T, oA + 2 * A_T);
        step(stD, oY + 3 * Y_T);  refill(stD, oB + 3 * B4_T, oX + 3 * X4_T, oA + 3 * A_T);
        oB += 4u * B4_T;
        oX += 4u * X4_T;
        oA += 4u * A_T;
        oY += 4u * Y_T;
    }
    // tail: consume t = T-4..T-1, no refill
    step(stA, oY);
    step(stB, oY + Y_T);
    step(stC, oY + 2 * Y_T);
    step(stD, oY + 3 * Y_T);

    Hf_[((size_t)bh * DS + n) * HD + p] = H;
}

// ---------------- pass 2: out = y * silu(z + y), in place ------------------
__global__ __launch_bounds__(256)
void gate_kernel(float* __restrict__ y_, const float* __restrict__ z_) {
    int i = blockIdx.x * 256 + threadIdx.x;          // float4 index
    float4 y4 = ((const float4*)y_)[i];
    float4 z4 = ((const float4*)z_)[i];
    float4 o;
    o.x = y4.x * fast_silu(z4.x + y4.x);
    o.y = y4.y * fast_silu(z4.y + y4.y);
    o.z = y4.z * fast_silu(z4.z + y4.z);
    o.w = y4.w * fast_silu(z4.w + y4.w);
    ((float4*)y_)[i] = o;
}
} // namespace

extern "C" void kernel_launch(void* const* d_in, const int* in_sizes, int n_in,
                              void* d_out, int out_size, void* d_ws, size_t ws_size,
                              hipStream_t stream) {
    const float* B_proj     = (const float*)d_in[0];
    const float* X_proj     = (const float*)d_in[1];
    const float* alpha_raw  = (const float*)d_in[2];
    const float* alpha_bias = (const float*)d_in[3];
    const float* z          = (const float*)d_in[4];
    const float* H0         = (const float*)d_in[5];

    float* out = (float*)d_out;                       // [T,BS,DI] then Hf
    float* Hf  = out + (size_t)T * BS * DI;

    const size_t alpha_bytes = (size_t)T * BS * NH * sizeof(float);
    if (ws_size >= alpha_bytes) {
        float* aw = (float*)d_ws;
        alpha_kernel<<<T * BS * NH / 256, 256, 0, stream>>>(alpha_raw, alpha_bias, aw);
        elman_scan_kernel<true><<<1024, 256, 0, stream>>>(
            (const float4*)B_proj, (const float4*)X_proj, aw, alpha_bias, H0, out, Hf);
    } else {
        elman_scan_kernel<false><<<1024, 256, 0, stream>>>(
            (const float4*)B_proj, (const float4*)X_proj, alpha_raw, alpha_bias, H0, out, Hf);
    }
    gate_kernel<<<(T * BS * DI / 4) / 256, 256, 0, stream>>>(out, z);
}

// Round 7
// 450.341 us; speedup vs baseline: 2.8723x; 1.6305x over previous
//
#include <hip/hip_runtime.h>
#include <hip/hip_bf16.h>

// StructuredElmanCell via MFMA with split-precision (hi/lo) bf16 inputs.
// Per (t,b,h): U[32,128] = B[32,8] @ X[128,8]^T. Wave owns a 16n x 16p H-tile
// in fp32 registers for all 1024 steps. K=8 real, K=32 capacity: lane groups
// carry (B_hi*X_hi)+(B_hi*X_lo)+(B_lo*X_hi)+(B_lo*X_lo) = ~fp32-accuracy
// product in ONE mfma_f32_16x16x32_bf16.
// R6 bug fixed: z is PER-TIMESTEP [T,BS,DI] — now in the prefetch ring
// (R5/R6 gated every step with z[t=0]; identical absmax 576 both rounds was
// the tell that the error was structural, not quantization).

namespace {
constexpr int T  = 1024;
constexpr int BS = 4;
constexpr int NH = 16;
constexpr int DS = 32;
constexpr int HD = 128;
constexpr int R  = 8;
constexpr int DI = NH * HD;                  // 2048

constexpr unsigned BF_T  = BS * NH * DS * R; // 16384 floats per t (B_proj)
constexpr unsigned XF_T  = BS * NH * HD * R; // 65536 floats per t (X_proj)
constexpr unsigned OUT_T = BS * DI;          // 8192 floats per t (z and out)
constexpr int DEPTH = 8;                     // prefetch ring depth (timesteps)

constexpr float LOG2E = 1.4426950408889634f;

typedef __attribute__((ext_vector_type(8))) short bf16x8;
typedef __attribute__((ext_vector_type(4))) float f32x4;
typedef __attribute__((ext_vector_type(4))) unsigned u32x4;

__device__ __forceinline__ float fast_exp(float x) {
    return __builtin_amdgcn_exp2f(x * LOG2E);
}
__device__ __forceinline__ float fast_silu(float x) {
    return x * __builtin_amdgcn_rcpf(1.0f + __builtin_amdgcn_exp2f(x * -LOG2E));
}

// Select hi (top-16 truncation) or lo (exact remainder) of two floats and pack
// their bf16-truncations into one u32: low16 = a's, high16 = b's.
__device__ __forceinline__ unsigned pack2_sel(float a, float b, bool hi) {
    unsigned ba = __float_as_uint(a), bb = __float_as_uint(b);
    float ha = __uint_as_float(ba & 0xffff0000u);
    float hb = __uint_as_float(bb & 0xffff0000u);
    float va = hi ? ha : (a - ha);       // a - ha is EXACT in fp32
    float vb = hi ? hb : (b - hb);
    // v_perm_b32: high half of va -> low16, high half of vb -> high16
    return __builtin_amdgcn_perm(__float_as_uint(vb), __float_as_uint(va),
                                 0x07060302u);
}

// ---------------- pass 0: alpha = 1/(2+exp(ar+ab)) == sigmoid(-softplus) ---
__global__ __launch_bounds__(256)
void alpha_kernel(const float* __restrict__ ar_, const float* __restrict__ ab_,
                  float* __restrict__ alpha_) {
    int i = blockIdx.x * 256 + threadIdx.x;          // [T,BS,NH] flat
    float v = ar_[i] + ab_[i & (NH - 1)];
    alpha_[i] = __builtin_amdgcn_rcpf(2.0f + fast_exp(v));
}

// ---------------- pass 1: MFMA scan ----------------------------------------
template<bool PRE>
__global__ __launch_bounds__(256, 1)
void elman_mfma_kernel(const float* __restrict__ B_,
                       const float* __restrict__ X_,
                       const float* __restrict__ a_,   // PRE? alpha : alpha_raw
                       const float* __restrict__ ab_,
                       const float* __restrict__ z_,
                       const float* __restrict__ H0_,
                       float* __restrict__ out_,
                       float* __restrict__ Hf_)
{
    __shared__ float ybuf[2][2][16];   // [step parity][pc-within-block][16 p]

    const int lane = threadIdx.x & 63;
    const int W    = blockIdx.x * 4 + (threadIdx.x >> 6); // 0..1023
    const int nc   = W & 1;            // n-chunk (0: n 0..15, 1: n 16..31)
    const int pc   = (W >> 1) & 7;     // p-chunk of 16
    const int bh   = W >> 4;           // 0..63
    const int h    = bh & (NH - 1);
    const int b    = bh >> 4;
    const int n0   = nc * 16;
    const int p0   = pc * 16;
    const int pcl  = pc & 1;           // pc within block (block = 2pc x 2nc)
    const int l15  = lane & 15;
    const bool ld  = lane < 16;

    // lane group g = lane>>4 carries one K-octet of the K=32 contraction.
    // g0:(Bhi,Xhi) g1:(Bhi,Xlo) g2:(Blo,Xhi) g3:(Blo,Xlo) -> sums to full product
    const bool useBhi = (lane < 32);
    const bool useXhi = ((lane & 16) == 0);

    // H[i] at n = n0 + (lane>>4)*4 + i, p = p0 + l15 (C/D layout)
    const unsigned hoff = (unsigned)bh * 4096u
                        + (unsigned)(n0 + (lane >> 4) * 4) * 128u
                        + (unsigned)(p0 + l15);
    f32x4 H;
    H.x = H0_[hoff];       H.y = H0_[hoff + 128];
    H.z = H0_[hoff + 256]; H.w = H0_[hoff + 384];

    const float abv = PRE ? 0.0f : ab_[h];

    // per-lane element offsets (all 4 k-groups load the same 16 rows)
    unsigned oB = (unsigned)bh * (DS * R) + (unsigned)(n0 + l15) * R;  // + t*BF_T
    unsigned oX = (unsigned)bh * (HD * R) + (unsigned)(p0 + l15) * R;  // + t*XF_T
    unsigned oA = (unsigned)bh;                                        // + t*64
    unsigned oO = (unsigned)b * DI + (unsigned)h * HD + p0 + l15;      // + t*OUT_T
    unsigned oZ = oO;                                                  // z: same layout

    float4 sB0[DEPTH], sB1[DEPTH], sX0[DEPTH], sX1[DEPTH];
    float  sAl[DEPTH], sZ[DEPTH];
    #pragma unroll
    for (int s = 0; s < DEPTH; ++s) {
        sB0[s] = *(const float4*)(B_ + oB + (unsigned)s * BF_T);
        sB1[s] = *(const float4*)(B_ + oB + (unsigned)s * BF_T + 4u);
        sX0[s] = *(const float4*)(X_ + oX + (unsigned)s * XF_T);
        sX1[s] = *(const float4*)(X_ + oX + (unsigned)s * XF_T + 4u);
        sAl[s] = a_[oA + (unsigned)s * 64u];
        sZ[s]  = z_[oZ + (unsigned)s * OUT_T];
    }
    oB += (unsigned)DEPTH * BF_T;
    oX += (unsigned)DEPTH * XF_T;
    oA += (unsigned)DEPTH * 64u;
    oZ += (unsigned)DEPTH * OUT_T;

    auto build = [](const float4& v0, const float4& v1, bool hi) -> bf16x8 {
        u32x4 u;
        u.x = pack2_sel(v0.x, v0.y, hi);
        u.y = pack2_sel(v0.z, v0.w, hi);
        u.z = pack2_sel(v1.x, v1.y, hi);
        u.w = pack2_sel(v1.z, v1.w, hi);
        return __builtin_bit_cast(bf16x8, u);
    };

    auto do_step = [&](int s, int par, unsigned oOcur) {
        bf16x8 af = build(sB0[s], sB1[s], useBhi);
        bf16x8 bf = build(sX0[s], sX1[s], useXhi);

        float ar    = __int_as_float(
                          __builtin_amdgcn_readfirstlane(__float_as_int(sAl[s])));
        float alpha = PRE ? ar
                          : __builtin_amdgcn_rcpf(2.0f + fast_exp(ar + abv));

        f32x4 c;
        c.x = alpha * H.x; c.y = alpha * H.y;
        c.z = alpha * H.z; c.w = alpha * H.w;
        f32x4 d = __builtin_amdgcn_mfma_f32_16x16x32_bf16(af, bf, c, 0, 0, 0);

        H.x = fast_silu(d.x); H.y = fast_silu(d.y);
        H.z = fast_silu(d.z); H.w = fast_silu(d.w);

        // partial y over this wave's 16 n-rows
        float y = (H.x + H.y) + (H.z + H.w);
        y += __shfl_xor(y, 16, 64);
        y += __shfl_xor(y, 32, 64);

        // cross-wave combine (nc pair in same block), parity double-buffered
        if (nc && ld) ybuf[par][pcl][l15] = y;
        asm volatile("s_waitcnt lgkmcnt(0)" ::: "memory");
        __builtin_amdgcn_s_barrier();
        asm volatile("" ::: "memory");
        if (!nc) {
            float y2 = y + ybuf[par][pcl][l15];
            float g  = y2 * fast_silu(sZ[s] + y2);
            if (ld) out_[oOcur] = g;
        }
    };

    #pragma unroll 1
    for (int t = 0; t < T - DEPTH; t += DEPTH) {
        #pragma unroll
        for (int s = 0; s < DEPTH; ++s) {
            do_step(s, s & 1, oO);
            // refill stage s with timestep t+s+DEPTH
            sB0[s] = *(const float4*)(B_ + oB + (unsigned)s * BF_T);
            sB1[s] = *(const float4*)(B_ + oB + (unsigned)s * BF_T + 4u);
            sX0[s] = *(const float4*)(X_ + oX + (unsigned)s * XF_T);
            sX1[s] = *(const float4*)(X_ + oX + (unsigned)s * XF_T + 4u);
            sAl[s] = a_[oA + (unsigned)s * 64u];
            sZ[s]  = z_[oZ + (unsigned)s * OUT_T];
            oO += OUT_T;
        }
        oB += (unsigned)DEPTH * BF_T;
        oX += (unsigned)DEPTH * XF_T;
        oA += (unsigned)DEPTH * 64u;
        oZ += (unsigned)DEPTH * OUT_T;
    }
    // tail: consume last DEPTH steps, no refill
    #pragma unroll
    for (int s = 0; s < DEPTH; ++s) {
        do_step(s, s & 1, oO);
        oO += OUT_T;
    }

    // H_final [BS,NH,DS,HD]
    Hf_[hoff]       = H.x;
    Hf_[hoff + 128] = H.y;
    Hf_[hoff + 256] = H.z;
    Hf_[hoff + 384] = H.w;
}
} // namespace

extern "C" void kernel_launch(void* const* d_in, const int* in_sizes, int n_in,
                              void* d_out, int out_size, void* d_ws, size_t ws_size,
                              hipStream_t stream) {
    const float* B_proj     = (const float*)d_in[0];
    const float* X_proj     = (const float*)d_in[1];
    const float* alpha_raw  = (const float*)d_in[2];
    const float* alpha_bias = (const float*)d_in[3];
    const float* z          = (const float*)d_in[4];
    const float* H0         = (const float*)d_in[5];

    float* out = (float*)d_out;                       // [T,BS,DI] then Hf
    float* Hf  = out + (size_t)T * BS * DI;

    const size_t alpha_bytes = (size_t)T * BS * NH * sizeof(float);
    if (ws_size >= alpha_bytes) {
        float* aw = (float*)d_ws;
        alpha_kernel<<<T * BS * NH / 256, 256, 0, stream>>>(alpha_raw, alpha_bias, aw);
        elman_mfma_kernel<true><<<256, 256, 0, stream>>>(
            B_proj, X_proj, aw, alpha_bias, z, H0, out, Hf);
    } else {
        elman_mfma_kernel<false><<<256, 256, 0, stream>>>(
            B_proj, X_proj, alpha_raw, alpha_bias, z, H0, out, Hf);
    }
}

// Round 8
// 320.233 us; speedup vs baseline: 4.0393x; 1.4063x over previous
//
#include <hip/hip_runtime.h>
#include <hip/hip_bf16.h>

// StructuredElmanCell via MFMA with split-precision (hi/lo) bf16 inputs.
// Per (t,b,h): U[32,128] = B[32,8] @ X[128,8]^T. Wave owns a 16n x 16p H-tile
// in fp32 registers for all 1024 steps. K=8 real, K=32 capacity: lane groups
// carry (B_hi*X_hi)+(B_hi*X_lo)+(B_lo*X_hi)+(B_lo*X_lo) = ~fp32-accuracy
// product in ONE mfma_f32_16x16x32_bf16.
// R8: cross-wave y-exchange batched 8 steps per barrier (R7 ran a 4-wave
// s_barrier EVERY step -> ~1148 cy/step wall vs ~250 cy of issue work).
// Partial-y and z banked in statically-indexed regs; one barrier per group.

namespace {
constexpr int T  = 1024;
constexpr int BS = 4;
constexpr int NH = 16;
constexpr int DS = 32;
constexpr int HD = 128;
constexpr int R  = 8;
constexpr int DI = NH * HD;                  // 2048

constexpr unsigned BF_T  = BS * NH * DS * R; // 16384 floats per t (B_proj)
constexpr unsigned XF_T  = BS * NH * HD * R; // 65536 floats per t (X_proj)
constexpr unsigned OUT_T = BS * DI;          // 8192 floats per t (z and out)
constexpr int DEPTH = 8;                     // prefetch ring depth = group size

constexpr float LOG2E = 1.4426950408889634f;

typedef __attribute__((ext_vector_type(8))) short bf16x8;
typedef __attribute__((ext_vector_type(4))) float f32x4;
typedef __attribute__((ext_vector_type(4))) unsigned u32x4;

__device__ __forceinline__ float fast_exp(float x) {
    return __builtin_amdgcn_exp2f(x * LOG2E);
}
__device__ __forceinline__ float fast_silu(float x) {
    return x * __builtin_amdgcn_rcpf(1.0f + __builtin_amdgcn_exp2f(x * -LOG2E));
}

// Select hi (top-16 truncation) or lo (exact remainder) of two floats and pack
// their bf16-truncations into one u32: low16 = a's, high16 = b's.
__device__ __forceinline__ unsigned pack2_sel(float a, float b, bool hi) {
    unsigned ba = __float_as_uint(a), bb = __float_as_uint(b);
    float ha = __uint_as_float(ba & 0xffff0000u);
    float hb = __uint_as_float(bb & 0xffff0000u);
    float va = hi ? ha : (a - ha);       // a - ha is EXACT in fp32
    float vb = hi ? hb : (b - hb);
    return __builtin_amdgcn_perm(__float_as_uint(vb), __float_as_uint(va),
                                 0x07060302u);
}

// ---------------- pass 0: alpha = 1/(2+exp(ar+ab)) == sigmoid(-softplus) ---
__global__ __launch_bounds__(256)
void alpha_kernel(const float* __restrict__ ar_, const float* __restrict__ ab_,
                  float* __restrict__ alpha_) {
    int i = blockIdx.x * 256 + threadIdx.x;          // [T,BS,NH] flat
    float v = ar_[i] + ab_[i & (NH - 1)];
    alpha_[i] = __builtin_amdgcn_rcpf(2.0f + fast_exp(v));
}

// ---------------- pass 1: MFMA scan ----------------------------------------
template<bool PRE>
__global__ __launch_bounds__(256, 1)
void elman_mfma_kernel(const float* __restrict__ B_,
                       const float* __restrict__ X_,
                       const float* __restrict__ a_,   // PRE? alpha : alpha_raw
                       const float* __restrict__ ab_,
                       const float* __restrict__ z_,
                       const float* __restrict__ H0_,
                       float* __restrict__ out_,
                       float* __restrict__ Hf_)
{
    __shared__ float ybuf[2][2][DEPTH][16];  // [group parity][pcl][stage][16 p]

    const int lane = threadIdx.x & 63;
    const int W    = blockIdx.x * 4 + (threadIdx.x >> 6); // 0..1023
    const int nc   = W & 1;            // n-chunk (0: n 0..15, 1: n 16..31)
    const int pc   = (W >> 1) & 7;     // p-chunk of 16
    const int bh   = W >> 4;           // 0..63
    const int h    = bh & (NH - 1);
    const int b    = bh >> 4;
    const int n0   = nc * 16;
    const int p0   = pc * 16;
    const int pcl  = pc & 1;           // pc within block (block = 2pc x 2nc)
    const int l15  = lane & 15;
    const bool ld  = lane < 16;

    // lane group g = lane>>4 carries one K-octet of the K=32 contraction.
    // g0:(Bhi,Xhi) g1:(Bhi,Xlo) g2:(Blo,Xhi) g3:(Blo,Xlo)
    const bool useBhi = (lane < 32);
    const bool useXhi = ((lane & 16) == 0);

    // H[i] at n = n0 + (lane>>4)*4 + i, p = p0 + l15 (C/D layout)
    const unsigned hoff = (unsigned)bh * 4096u
                        + (unsigned)(n0 + (lane >> 4) * 4) * 128u
                        + (unsigned)(p0 + l15);
    f32x4 H;
    H.x = H0_[hoff];       H.y = H0_[hoff + 128];
    H.z = H0_[hoff + 256]; H.w = H0_[hoff + 384];

    const float abv = PRE ? 0.0f : ab_[h];

    unsigned oB = (unsigned)bh * (DS * R) + (unsigned)(n0 + l15) * R;  // + t*BF_T
    unsigned oX = (unsigned)bh * (HD * R) + (unsigned)(p0 + l15) * R;  // + t*XF_T
    unsigned oA = (unsigned)bh;                                        // + t*64
    unsigned oO = (unsigned)b * DI + (unsigned)h * HD + p0 + l15;      // + t*OUT_T
    unsigned oZ = oO;

    float4 sB0[DEPTH], sB1[DEPTH], sX0[DEPTH], sX1[DEPTH];
    float  sAl[DEPTH], sZ[DEPTH];
    #pragma unroll
    for (int s = 0; s < DEPTH; ++s) {
        sB0[s] = *(const float4*)(B_ + oB + (unsigned)s * BF_T);
        sB1[s] = *(const float4*)(B_ + oB + (unsigned)s * BF_T + 4u);
        sX0[s] = *(const float4*)(X_ + oX + (unsigned)s * XF_T);
        sX1[s] = *(const float4*)(X_ + oX + (unsigned)s * XF_T + 4u);
        sAl[s] = a_[oA + (unsigned)s * 64u];
        sZ[s]  = z_[oZ + (unsigned)s * OUT_T];
    }
    oB += (unsigned)DEPTH * BF_T;
    oX += (unsigned)DEPTH * XF_T;
    oA += (unsigned)DEPTH * 64u;
    oZ += (unsigned)DEPTH * OUT_T;

    auto build = [](const float4& v0, const float4& v1, bool hi) -> bf16x8 {
        u32x4 u;
        u.x = pack2_sel(v0.x, v0.y, hi);
        u.y = pack2_sel(v0.z, v0.w, hi);
        u.z = pack2_sel(v1.x, v1.y, hi);
        u.w = pack2_sel(v1.z, v1.w, hi);
        return __builtin_bit_cast(bf16x8, u);
    };

    // one recurrence step; returns this wave's 16-row partial y (all lanes)
    auto do_step = [&](int s) -> float {
        bf16x8 af = build(sB0[s], sB1[s], useBhi);
        bf16x8 bf = build(sX0[s], sX1[s], useXhi);

        float ar    = __int_as_float(
                          __builtin_amdgcn_readfirstlane(__float_as_int(sAl[s])));
        float alpha = PRE ? ar
                          : __builtin_amdgcn_rcpf(2.0f + fast_exp(ar + abv));

        f32x4 c;
        c.x = alpha * H.x; c.y = alpha * H.y;
        c.z = alpha * H.z; c.w = alpha * H.w;
        f32x4 d = __builtin_amdgcn_mfma_f32_16x16x32_bf16(af, bf, c, 0, 0, 0);

        H.x = fast_silu(d.x); H.y = fast_silu(d.y);
        H.z = fast_silu(d.z); H.w = fast_silu(d.w);

        float y = (H.x + H.y) + (H.z + H.w);
        y += __shfl_xor(y, 16, 64);
        y += __shfl_xor(y, 32, 64);
        return y;
    };

    float yb[DEPTH], zb[DEPTH];

    // exchange + gate + store for one finished group (parity gp, out base oOg)
    auto exchange = [&](int gp, unsigned oOg) {
        if (nc) {
            if (ld) {
                #pragma unroll
                for (int s = 0; s < DEPTH; ++s)
                    ybuf[gp][pcl][s][l15] = yb[s];
            }
            asm volatile("s_waitcnt lgkmcnt(0)" ::: "memory");
        }
        __builtin_amdgcn_s_barrier();
        __builtin_amdgcn_sched_barrier(0);
        asm volatile("" ::: "memory");
        if (!nc && ld) {
            #pragma unroll
            for (int s = 0; s < DEPTH; ++s) {
                float y2 = yb[s] + ybuf[gp][pcl][s][l15];
                float g  = y2 * fast_silu(zb[s] + y2);
                out_[oOg + (unsigned)s * OUT_T] = g;
            }
        }
    };

    int gp = 0;
    #pragma unroll 1
    for (int t = 0; t < T - DEPTH; t += DEPTH) {
        #pragma unroll
        for (int s = 0; s < DEPTH; ++s) {
            zb[s] = sZ[s];                 // preserve before refill
            yb[s] = do_step(s);
            // refill stage s with timestep t+s+DEPTH
            sB0[s] = *(const float4*)(B_ + oB + (unsigned)s * BF_T);
            sB1[s] = *(const float4*)(B_ + oB + (unsigned)s * BF_T + 4u);
            sX0[s] = *(const float4*)(X_ + oX + (unsigned)s * XF_T);
            sX1[s] = *(const float4*)(X_ + oX + (unsigned)s * XF_T + 4u);
            sAl[s] = a_[oA + (unsigned)s * 64u];
            sZ[s]  = z_[oZ + (unsigned)s * OUT_T];
        }
        exchange(gp, oO);
        gp ^= 1;
        oB += (unsigned)DEPTH * BF_T;
        oX += (unsigned)DEPTH * XF_T;
        oA += (unsigned)DEPTH * 64u;
        oZ += (unsigned)DEPTH * OUT_T;
        oO += (unsigned)DEPTH * OUT_T;
    }
    // tail group: consume last DEPTH steps, no refill
    #pragma unroll
    for (int s = 0; s < DEPTH; ++s) {
        zb[s] = sZ[s];
        yb[s] = do_step(s);
    }
    exchange(gp, oO);

    // H_final [BS,NH,DS,HD]
    Hf_[hoff]       = H.x;
    Hf_[hoff + 128] = H.y;
    Hf_[hoff + 256] = H.z;
    Hf_[hoff + 384] = H.w;
}
} // namespace

extern "C" void kernel_launch(void* const* d_in, const int* in_sizes, int n_in,
                              void* d_out, int out_size, void* d_ws, size_t ws_size,
                              hipStream_t stream) {
    const float* B_proj     = (const float*)d_in[0];
    const float* X_proj     = (const float*)d_in[1];
    const float* alpha_raw  = (const float*)d_in[2];
    const float* alpha_bias = (const float*)d_in[3];
    const float* z          = (const float*)d_in[4];
    const float* H0         = (const float*)d_in[5];

    float* out = (float*)d_out;                       // [T,BS,DI] then Hf
    float* Hf  = out + (size_t)T * BS * DI;

    const size_t alpha_bytes = (size_t)T * BS * NH * sizeof(float);
    if (ws_size >= alpha_bytes) {
        float* aw = (float*)d_ws;
        alpha_kernel<<<T * BS * NH / 256, 256, 0, stream>>>(alpha_raw, alpha_bias, aw);
        elman_mfma_kernel<true><<<256, 256, 0, stream>>>(
            B_proj, X_proj, aw, alpha_bias, z, H0, out, Hf);
    } else {
        elman_mfma_kernel<false><<<256, 256, 0, stream>>>(
            B_proj, X_proj, alpha_raw, alpha_bias, z, H0, out, Hf);
    }
}

// Round 9
// 308.535 us; speedup vs baseline: 4.1925x; 1.0379x over previous
//
#include <hip/hip_runtime.h>

// StructuredElmanCell via MFMA, split-precision (hi/lo) bf16 inputs.
// Wave owns a 16n x 16p H-tile in fp32 regs for all 1024 steps; K=32 MFMA
// carries (Bhi*Xhi)+(Bhi*Xlo)+(Blo*Xhi)+(Blo*Xlo) across its 4 k-octets.
// R9: dual packed-fragment sets -- pack of group g+1 is interleaved into the
// stall slots of group g's MFMA->silu latency chain; no per-step shfl (per-lane
// partials banked, one LDS exchange + barrier per 8 steps, gate split across
// all 4 waves); 1 z/alpha load per lane per group; byte-offset addressing.

namespace {
constexpr int T  = 1024;
constexpr int BS = 4;
constexpr int NH = 16;
constexpr int DS = 32;
constexpr int HD = 128;
constexpr int R  = 8;
constexpr int DI = NH * HD;              // 2048
constexpr int GROUP = 8;

// byte strides
constexpr unsigned B_T  = BS * NH * DS * R * 4;  // 65536 B per t
constexpr unsigned X_T  = BS * NH * HD * R * 4;  // 262144 B per t
constexpr unsigned B_G  = B_T * GROUP;
constexpr unsigned X_G  = X_T * GROUP;
constexpr unsigned A_G  = BS * NH * 4 * GROUP;   // 2048 B per group
constexpr unsigned ZO_T = BS * DI * 4;           // 32768 B per t (z and out)
constexpr unsigned ZO_G = ZO_T * GROUP;          // 262144 B per group

constexpr float LOG2E = 1.4426950408889634f;

typedef __attribute__((ext_vector_type(8))) short bf16x8;
typedef __attribute__((ext_vector_type(4))) float f32x4;
typedef __attribute__((ext_vector_type(4))) unsigned u32x4;

__device__ __forceinline__ float fast_exp(float x) {
    return __builtin_amdgcn_exp2f(x * LOG2E);
}
__device__ __forceinline__ float fast_silu(float x) {
    return x * __builtin_amdgcn_rcpf(1.0f + __builtin_amdgcn_exp2f(x * -LOG2E));
}
__device__ __forceinline__ float4 ld4(const void* p, unsigned off) {
    return *(const float4*)((const char*)p + off);
}
__device__ __forceinline__ float ld1(const void* p, unsigned off) {
    return *(const float*)((const char*)p + off);
}

// bf16-pair pack: low16 = sel(a), high16 = sel(b); hi = top-16 truncation,
// lo = exact fp32 remainder truncated to bf16.
__device__ __forceinline__ unsigned pack_pair(float a, float b, bool useHi) {
    unsigned ua = __float_as_uint(a), ub = __float_as_uint(b);
    unsigned hi = __builtin_amdgcn_perm(ub, ua, 0x07060302u);
    float la = a - __uint_as_float(ua & 0xffff0000u);   // exact
    float lb = b - __uint_as_float(ub & 0xffff0000u);
    unsigned lo = __builtin_amdgcn_perm(__float_as_uint(lb),
                                        __float_as_uint(la), 0x07060302u);
    return useHi ? hi : lo;
}
__device__ __forceinline__ u32x4 pack_frag(const float4& v0, const float4& v1,
                                           bool useHi) {
    u32x4 u;
    u.x = pack_pair(v0.x, v0.y, useHi);
    u.y = pack_pair(v0.z, v0.w, useHi);
    u.z = pack_pair(v1.x, v1.y, useHi);
    u.w = pack_pair(v1.z, v1.w, useHi);
    return u;
}

// ---------------- pass 0: alpha = 1/(2+exp(ar+ab)) == sigmoid(-softplus) ---
__global__ __launch_bounds__(256)
void alpha_kernel(const float* __restrict__ ar_, const float* __restrict__ ab_,
                  float* __restrict__ alpha_) {
    int i = blockIdx.x * 256 + threadIdx.x;          // [T,BS,NH] flat
    float v = ar_[i] + ab_[i & (NH - 1)];
    alpha_[i] = __builtin_amdgcn_rcpf(2.0f + fast_exp(v));
}

// ---------------- pass 1: MFMA scan ----------------------------------------
template<bool PRE>
__global__ __launch_bounds__(256, 1)
void elman_mfma_kernel(const float* __restrict__ B_,
                       const float* __restrict__ X_,
                       const float* __restrict__ a_,   // PRE? alpha : alpha_raw
                       const float* __restrict__ ab_,
                       const float* __restrict__ z_,
                       const float* __restrict__ H0_,
                       float* __restrict__ out_,
                       float* __restrict__ Hf_)
{
    __shared__ float ybuf[2][2][GROUP][8][17];  // [parity][pcl][stage][src][p]

    const int lane = threadIdx.x & 63;
    const int W    = blockIdx.x * 4 + (threadIdx.x >> 6); // 0..1023
    const int nc   = W & 1;
    const int pc   = (W >> 1) & 7;
    const int bh   = W >> 4;
    const int h    = bh & (NH - 1);
    const int b    = bh >> 4;
    const int n0   = nc * 16;
    const int p0   = pc * 16;
    const int pcl  = pc & 1;
    const int l15  = lane & 15;
    const int sl   = lane >> 4;          // 0..3
    const int st   = nc * 4 + sl;        // this lane's gate stage AND src id

    const bool useBhi = (lane < 32);
    const bool useXhi = ((lane & 16) == 0);

    const unsigned hoff = (unsigned)bh * 4096u
                        + (unsigned)(n0 + sl * 4) * 128u
                        + (unsigned)(p0 + l15);
    f32x4 H;
    H.x = H0_[hoff];       H.y = H0_[hoff + 128];
    H.z = H0_[hoff + 256]; H.w = H0_[hoff + 384];

    const float abv = PRE ? 0.0f : ab_[h];

    // byte offsets off SGPR bases
    unsigned bB = ((unsigned)bh * (DS * R) + (unsigned)(n0 + l15) * R) * 4u;
    unsigned bX = ((unsigned)bh * (HD * R) + (unsigned)(p0 + l15) * R) * 4u;
    unsigned bA = ((unsigned)(lane & 7) * 64u + (unsigned)bh) * 4u;
    const unsigned zo0 = ((unsigned)st * 8192u + (unsigned)b * 2048u
                        + (unsigned)h * 128u + (unsigned)(p0 + l15)) * 4u;
    unsigned bZ = zo0, bO = zo0;

    float4 rB0[GROUP], rB1[GROUP], rX0[GROUP], rX1[GROUP];
    u32x4 A0[GROUP], B0f[GROUP], A1[GROUP], B1f[GROUP];
    float py[GROUP];
    float avA, avB, zvA, zvB;

    // ---- prologue: raw g0 -> pack into set0; raw g1 into ring -------------
    #pragma unroll
    for (int s = 0; s < GROUP; ++s) {
        rB0[s] = ld4(B_, bB + (unsigned)s * B_T);
        rB1[s] = ld4(B_, bB + (unsigned)s * B_T + 16u);
        rX0[s] = ld4(X_, bX + (unsigned)s * X_T);
        rX1[s] = ld4(X_, bX + (unsigned)s * X_T + 16u);
    }
    bB += B_G; bX += X_G;
    avA = ld1(a_, bA); bA += A_G;
    zvA = ld1(z_, bZ); bZ += ZO_G;
    #pragma unroll
    for (int s = 0; s < GROUP; ++s) {
        A0[s]  = pack_frag(rB0[s], rB1[s], useBhi);
        B0f[s] = pack_frag(rX0[s], rX1[s], useXhi);
    }
    #pragma unroll
    for (int s = 0; s < GROUP; ++s) {
        rB0[s] = ld4(B_, bB + (unsigned)s * B_T);
        rB1[s] = ld4(B_, bB + (unsigned)s * B_T + 16u);
        rX0[s] = ld4(X_, bX + (unsigned)s * X_T);
        rX1[s] = ld4(X_, bX + (unsigned)s * X_T + 16u);
    }
    bB += B_G; bX += X_G;   // now points at g2

    auto step = [&](const u32x4& af, const u32x4& bf, float avC, int s) {
        float ar = __int_as_float(
            __builtin_amdgcn_readlane(__float_as_int(avC), s));
        float alpha = PRE ? ar
                          : __builtin_amdgcn_rcpf(2.0f + fast_exp(ar + abv));
        f32x4 c;
        c.x = alpha * H.x; c.y = alpha * H.y;
        c.z = alpha * H.z; c.w = alpha * H.w;
        f32x4 d = __builtin_amdgcn_mfma_f32_16x16x32_bf16(
            __builtin_bit_cast(bf16x8, af), __builtin_bit_cast(bf16x8, bf),
            c, 0, 0, 0);
        H.x = fast_silu(d.x); H.y = fast_silu(d.y);
        H.z = fast_silu(d.z); H.w = fast_silu(d.w);
        py[s] = (H.x + H.y) + (H.z + H.w);
    };

    auto exchange = [&](int par, float zvC) {
        #pragma unroll
        for (int s = 0; s < GROUP; ++s)
            ybuf[par][pcl][s][st][l15] = py[s];
        asm volatile("s_waitcnt lgkmcnt(0)" ::: "memory");
        __builtin_amdgcn_s_barrier();
        __builtin_amdgcn_sched_barrier(0);
        asm volatile("" ::: "memory");
        float y2 = 0.0f;
        #pragma unroll
        for (int k = 0; k < 8; ++k)
            y2 += ybuf[par][pcl][st][k][l15];
        float g = y2 * fast_silu(zvC + y2);
        *(float*)((char*)out_ + bO) = g;
        bO += ZO_G;
    };

    // body for one group: steps from (Ac,Bc); pack ring -> (An,Bn); refill ring
    auto body = [&](u32x4 (&Ac)[GROUP], u32x4 (&Bc)[GROUP],
                    u32x4 (&An)[GROUP], u32x4 (&Bn)[GROUP],
                    float avC, float& avN, float zvC, float& zvN,
                    int par, bool refill) {
        avN = ld1(a_, bA); bA += A_G;
        zvN = ld1(z_, bZ); bZ += ZO_G;
        #pragma unroll
        for (int s = 0; s < GROUP; ++s) {
            step(Ac[s], Bc[s], avC, s);
            An[s] = pack_frag(rB0[s], rB1[s], useBhi);
            Bn[s] = pack_frag(rX0[s], rX1[s], useXhi);
            if (refill) {
                rB0[s] = ld4(B_, bB + (unsigned)s * B_T);
                rB1[s] = ld4(B_, bB + (unsigned)s * B_T + 16u);
                rX0[s] = ld4(X_, bX + (unsigned)s * X_T);
                rX1[s] = ld4(X_, bX + (unsigned)s * X_T + 16u);
            }
        }
        if (refill) { bB += B_G; bX += X_G; }
        exchange(par, zvC);
    };

    // main: groups 0..125 (refill g+2 valid through g=125 -> loads g127)
    #pragma unroll 1
    for (int gg = 0; gg < 63; ++gg) {
        body(A0, B0f, A1, B1f, avA, avB, zvA, zvB, 0, true);
        body(A1, B1f, A0, B0f, avB, avA, zvB, zvA, 1, true);
    }
    // group 126: pack g127 from ring, no refill
    body(A0, B0f, A1, B1f, avA, avB, zvA, zvB, 0, false);
    // group 127: steps only
    #pragma unroll
    for (int s = 0; s < GROUP; ++s)
        step(A1[s], B1f[s], avB, s);
    exchange(1, zvB);

    // H_final [BS,NH,DS,HD]
    Hf_[hoff]       = H.x;
    Hf_[hoff + 128] = H.y;
    Hf_[hoff + 256] = H.z;
    Hf_[hoff + 384] = H.w;
}
} // namespace

extern "C" void kernel_launch(void* const* d_in, const int* in_sizes, int n_in,
                              void* d_out, int out_size, void* d_ws, size_t ws_size,
                              hipStream_t stream) {
    const float* B_proj     = (const float*)d_in[0];
    const float* X_proj     = (const float*)d_in[1];
    const float* alpha_raw  = (const float*)d_in[2];
    const float* alpha_bias = (const float*)d_in[3];
    const float* z          = (const float*)d_in[4];
    const float* H0         = (const float*)d_in[5];

    float* out = (float*)d_out;                       // [T,BS,DI] then Hf
    float* Hf  = out + (size_t)T * BS * DI;

    const size_t alpha_bytes = (size_t)T * BS * NH * sizeof(float);
    if (ws_size >= alpha_bytes) {
        float* aw = (float*)d_ws;
        alpha_kernel<<<T * BS * NH / 256, 256, 0, stream>>>(alpha_raw, alpha_bias, aw);
        elman_mfma_kernel<true><<<256, 256, 0, stream>>>(
            B_proj, X_proj, aw, alpha_bias, z, H0, out, Hf);
    } else {
        elman_mfma_kernel<false><<<256, 256, 0, stream>>>(
            B_proj, X_proj, alpha_raw, alpha_bias, z, H0, out, Hf);
    }
}